// Round 5
// baseline (311.942 us; speedup 1.0000x reference)
//
#include <hip/hip_runtime.h>
#include <stdint.h>

typedef unsigned short u16;
typedef unsigned int u32;

using bf16x8 = __attribute__((ext_vector_type(8))) short;
using f32x4  = __attribute__((ext_vector_type(4))) float;

#define DEVINL __device__ __forceinline__

DEVINL float b2f(u16 u) { return __builtin_bit_cast(float, (u32)u << 16); }
DEVINL u16 f2b(float f) {
  u32 u = __builtin_bit_cast(u32, f);
  u += 0x7FFFu + ((u >> 16) & 1u);   // round-to-nearest-even
  return (u16)(u >> 16);
}

DEVINL void gll16(const u16* src, u16* dst) {
  __builtin_amdgcn_global_load_lds(
      (const __attribute__((address_space(1))) void*)(uintptr_t)src,
      (__attribute__((address_space(3))) void*)(uintptr_t)dst, 16, 0, 0);
}

#define MFMA __builtin_amdgcn_mfma_f32_16x16x32_bf16
#define NROLE 6

// ---------------------------------------------------------------- mega0:
// transposes (blocks 0..1151) | role_count (1152..1279) | rnn copy (1280..1407).
DEVINL void tp_tile(const float* __restrict__ s, u16* __restrict__ d,
                    int R, int C, int bx, int by, int z)
{
  __shared__ u16 tile[32][33];
  const size_t mstride = (size_t)R * C;
  s += (size_t)z * mstride;
  d += (size_t)z * mstride;
  int r0 = bx * 32, c0 = by * 32;
  int tx = threadIdx.x & 31, ty = threadIdx.x >> 5;
#pragma unroll
  for (int i = 0; i < 32; i += 8)
    tile[ty + i][tx] = f2b(s[(size_t)(r0 + ty + i) * C + (c0 + tx)]);
  __syncthreads();
#pragma unroll
  for (int i = 0; i < 32; i += 8)
    d[(size_t)(c0 + ty + i) * R + (r0 + tx)] = tile[tx][ty + i];
}

__global__ __launch_bounds__(256) void mega0(
    const float* W0, const float* W1, const float* Wr0, const float* Wr1, const float* Wh0,
    u16* W0t, u16* W1t, u16* Wr0t, u16* Wr1t, u16* Wh0t,
    const int* __restrict__ rid, int* __restrict__ blkCnt,
    const float* __restrict__ rnn, float* __restrict__ outRnn)
{
  int b = blockIdx.x;
  const int tid = threadIdx.x;
  if (b < 1152) {
    if (b < 128)      {            tp_tile(W0, W0t, 256, 512, b % 8,  b / 8, 0); }
    else if (b < 384) { b -= 128;  tp_tile(W1, W1t, 512, 512, b % 16, b / 16, 0); }
    else if (b < 576) { b -= 384;  int t = b / 8;  tp_tile(Wr0, Wr0t, 256, 128, b % 8,  t % 4,  t / 4); }
    else if (b < 960) { b -= 576;  int t = b / 4;  tp_tile(Wr1, Wr1t, 128, 512, b % 4,  t % 16, t / 16); }
    else              { b -= 960;  int t = b / 16; tp_tile(Wh0, Wh0t, 512, 64,  b % 16, t % 2,  t / 2); }
  } else if (b < 1280) {
    b -= 1152;
    __shared__ int h[NROLE];
    if (tid < NROLE) h[tid] = 0;
    __syncthreads();
    atomicAdd(&h[rid[b * 256 + tid]], 1);
    __syncthreads();
    if (tid < NROLE) blkCnt[b * NROLE + tid] = h[tid];
  } else {
    b -= 1280;
    const float4* src = (const float4*)rnn;
    float4* dst = (float4*)outRnn;
    int base = (b * 256 + tid) * 4;
#pragma unroll
    for (int i = 0; i < 4; ++i) dst[base + i] = src[base + i];
  }
}

// ---------------------------------------------------------------- g0f (round-4 verified):
// blocks 0..511: fused obs-LN + gemm0 + ReLU + LN0; blocks 512..639: fill2.
__global__ __launch_bounds__(256, 2) void g0f(
    const float* __restrict__ obs, const float* __restrict__ fn_s,
    const float* __restrict__ fn_b, const u16* __restrict__ W0t,
    const float* __restrict__ b0, const float* __restrict__ ln0sc,
    const float* __restrict__ ln0bi, u16* __restrict__ obs_n,
    u16* __restrict__ C,
    const int* __restrict__ rid, const int* __restrict__ blkCnt,
    int* __restrict__ bucket, int* __restrict__ baseArr, int* __restrict__ cntArr)
{
  __shared__ __align__(16) u16 smem[20480];   // 40960 B
  const int tid = threadIdx.x;

  if (blockIdx.x >= 512) {
    const int bx = blockIdx.x - 512;
    int* c = (int*)smem;
    int* preArr = c + 768;
    int* scnt   = c + 776;
    int* sbase  = c + 784;
    int* h      = c + 792;
    for (int i = tid; i < 128 * NROLE; i += 256) c[i] = blkCnt[i];
    if (tid < NROLE) h[tid] = 0;
    __syncthreads();
    if (tid < NROLE) {
      int k = tid, run = 0, pre = 0;
      for (int b = 0; b < 128; ++b) { if (b == bx) pre = run; run += c[b * NROLE + k]; }
      scnt[k] = run; preArr[k] = pre;
    }
    __syncthreads();
    if (tid == 0) {
      int r = 0;
      for (int k = 0; k < NROLE; ++k) { sbase[k] = r; r += scnt[k]; }
    }
    __syncthreads();
    if (bx == 0 && tid < NROLE) { baseArr[tid] = sbase[tid]; cntArr[tid] = scnt[tid]; }
    int i = bx * 256 + tid;
    int k = rid[i];
    int pos = atomicAdd(&h[k], 1);
    bucket[sbase[k] + preArr[k] + pos] = i;
    return;
  }

  u16* smA     = smem;
  float* redS  = (float*)&smem[16384];
  float* redSS = (float*)&smem[16896];
  float* prm   = (float*)&smem[17408];
  const int rowBase = blockIdx.x * 64;
  const int lane = tid & 63, wave = tid >> 6;
  const int quad = lane >> 4, lm = lane & 15, l7 = lm & 7;

#pragma unroll
  for (int i = tid; i < 512; i += 256) {
    prm[i] = b0[i]; prm[512 + i] = ln0sc[i]; prm[1024 + i] = ln0bi[i];
  }

  {
    const int r = tid >> 2, q = tid & 3;
    const float* xr = obs + (size_t)(rowBase + r) * 256 + q * 64;
    float x[64];
#pragma unroll
    for (int jj = 0; jj < 16; ++jj)
      *(float4*)&x[jj * 4] = *(const float4*)(xr + jj * 4);
    float s = 0.f, s2 = 0.f;
#pragma unroll
    for (int p = 0; p < 64; ++p) { s += x[p]; s2 += x[p] * x[p]; }
    s  += __shfl_xor(s, 1, 64);  s  += __shfl_xor(s, 2, 64);
    s2 += __shfl_xor(s2, 1, 64); s2 += __shfl_xor(s2, 2, 64);
    float m = s * (1.f / 256.f);
    float var = s2 * (1.f / 256.f) - m * m;
    float inv = rsqrtf(var + 1e-5f);
    const float* fs = fn_s + q * 64;
    const float* fb = fn_b + q * 64;
    u16* og = obs_n + (size_t)(rowBase + r) * 256 + q * 64;
#pragma unroll
    for (int j = 0; j < 8; ++j) {
      float4 fs0 = *(const float4*)(fs + j * 8);
      float4 fs1 = *(const float4*)(fs + j * 8 + 4);
      float4 fb0 = *(const float4*)(fb + j * 8);
      float4 fb1 = *(const float4*)(fb + j * 8 + 4);
      u16 yy[8] __attribute__((aligned(16)));
      yy[0] = f2b((x[j*8+0] - m) * inv * fs0.x + fb0.x);
      yy[1] = f2b((x[j*8+1] - m) * inv * fs0.y + fb0.y);
      yy[2] = f2b((x[j*8+2] - m) * inv * fs0.z + fb0.z);
      yy[3] = f2b((x[j*8+3] - m) * inv * fs0.w + fb0.w);
      yy[4] = f2b((x[j*8+4] - m) * inv * fs1.x + fb1.x);
      yy[5] = f2b((x[j*8+5] - m) * inv * fs1.y + fb1.y);
      yy[6] = f2b((x[j*8+6] - m) * inv * fs1.z + fb1.z);
      yy[7] = f2b((x[j*8+7] - m) * inv * fs1.w + fb1.w);
      int cch = q * 8 + j;
      *(uint4*)&smA[r * 256 + ((cch ^ (r & 7)) * 8)] = *(uint4*)yy;
      *(uint4*)(og + j * 8) = *(uint4*)yy;
    }
  }

  const int wn = wave * 128;
  u32 bOff[8];
#pragma unroll
  for (int j = 0; j < 8; ++j)
    bOff[j] = (u32)(wn + j * 16 + lm) * 256u + (u32)(quad * 8);
  f32x4 acc[4][8] = {};
  bf16x8 bR[2][8];
#pragma unroll
  for (int p = 0; p < 2; ++p)
#pragma unroll
    for (int j = 0; j < 8; ++j)
      bR[p][j] = *(const bf16x8*)(W0t + bOff[j] + p * 32);
  __syncthreads();

#pragma unroll
  for (int g = 0; g < 8; ++g) {
    bf16x8 cur[8];
#pragma unroll
    for (int j = 0; j < 8; ++j) cur[j] = bR[g & 1][j];
    if (g + 2 < 8) {
#pragma unroll
      for (int j = 0; j < 8; ++j)
        bR[g & 1][j] = *(const bf16x8*)(W0t + bOff[j] + (g + 2) * 32);
    }
    const int kc = g * 4;
    bf16x8 af[4];
#pragma unroll
    for (int i2 = 0; i2 < 4; ++i2)
      af[i2] = *(const bf16x8*)&smA[(i2 * 16 + lm) * 256 + (((quad + kc) ^ l7) * 8)];
#pragma unroll
    for (int i2 = 0; i2 < 4; ++i2)
#pragma unroll
      for (int j = 0; j < 8; ++j)
        acc[i2][j] = MFMA(af[i2], cur[j], acc[i2][j], 0, 0, 0);
  }

#pragma unroll
  for (int i2 = 0; i2 < 4; ++i2) {
#pragma unroll
    for (int r2 = 0; r2 < 4; ++r2) {
      float s = 0.f, ss = 0.f;
#pragma unroll
      for (int j = 0; j < 8; ++j) {
        float v = fmaxf(acc[i2][j][r2] + prm[wn + j * 16 + lm], 0.f);
        acc[i2][j][r2] = v;
        s += v; ss += v * v;
      }
#pragma unroll
      for (int o = 1; o < 16; o <<= 1) { s += __shfl_xor(s, o, 64); ss += __shfl_xor(ss, o, 64); }
      if (lm == 0) {
        int rowL = i2 * 16 + quad * 4 + r2;
        redS[rowL * 4 + wave] = s;
        redSS[rowL * 4 + wave] = ss;
      }
    }
  }
  __syncthreads();
#pragma unroll
  for (int i2 = 0; i2 < 4; ++i2) {
#pragma unroll
    for (int r2 = 0; r2 < 4; ++r2) {
      int rowL = i2 * 16 + quad * 4 + r2;
      float ts  = redS[rowL * 4 + 0] + redS[rowL * 4 + 1] + redS[rowL * 4 + 2] + redS[rowL * 4 + 3];
      float tss = redSS[rowL * 4 + 0] + redSS[rowL * 4 + 1] + redSS[rowL * 4 + 2] + redSS[rowL * 4 + 3];
      float m = ts * (1.f / 512.f);
      float var = tss * (1.f / 512.f) - m * m;
      float inv = rsqrtf(var + 1e-5f);
      size_t base = (size_t)(rowBase + rowL) * 512;
#pragma unroll
      for (int j = 0; j < 8; ++j) {
        int col = wn + j * 16 + lm;
        float y = (acc[i2][j][r2] - m) * inv * prm[512 + col] + prm[1024 + col];
        C[base + col] = f2b(y);
      }
    }
  }
}

// ---------------------------------------------------------------- gemm_ln (round-4 verified, K=512)
template <int K>
__global__ __launch_bounds__(256, 2) void gemm_ln(
    const u16* __restrict__ A, const u16* __restrict__ Bt,
    const float* __restrict__ bias, const float* __restrict__ lnsc,
    const float* __restrict__ lnbi, u16* __restrict__ C)
{
  constexpr int BK = 128, NI = K / BK, NC = K / 32;
  __shared__ __align__(16) u16 As[2][64 * BK];
  __shared__ float redS[64][4];
  __shared__ float redSS[64][4];
  __shared__ float prm[1536];
  const int tid = threadIdx.x;
  const int rowBase = blockIdx.x * 64;
  const int lane = tid & 63, wave = tid >> 6;
#pragma unroll
  for (int i = tid; i < 512; i += 256) {
    prm[i] = bias[i]; prm[512 + i] = lnsc[i]; prm[1024 + i] = lnbi[i];
  }
  u32 aOff[4];
#pragma unroll
  for (int r = 0; r < 4; ++r) {
    int row = r * 16 + (tid >> 4);
    int chunk = tid & 15;
    aOff[r] = (u32)(rowBase + row) * (u32)K + (u32)((chunk ^ (row & 7)) * 8);
  }
  const int quad = lane >> 4, lm = lane & 15, l7 = lm & 7;
  const int wn = wave * 128;
  u32 bOff[8];
#pragma unroll
  for (int j = 0; j < 8; ++j)
    bOff[j] = (u32)(wn + j * 16 + lm) * (u32)K + (u32)(quad * 8);

  f32x4 acc[4][8] = {};

#pragma unroll
  for (int r = 0; r < 4; ++r)
    gll16(A + aOff[r], &As[0][r * 2048 + wave * 512]);
  bf16x8 bP[8];
#pragma unroll
  for (int j = 0; j < 8; ++j)
    bP[j] = *(const bf16x8*)(Bt + bOff[j]);
  __syncthreads();

  for (int i = 0; i < NI; ++i) {
    const u16* Ab = As[i & 1];
    if (i + 1 < NI) {
#pragma unroll
      for (int r = 0; r < 4; ++r)
        gll16(A + aOff[r] + (i + 1) * BK, &As[(i + 1) & 1][r * 2048 + wave * 512]);
    }
#pragma unroll
    for (int c = 0; c < 4; ++c) {
      const int g = i * 4 + c;
      bf16x8 bN[8];
      if (g + 1 < NC) {
#pragma unroll
        for (int j = 0; j < 8; ++j)
          bN[j] = *(const bf16x8*)(Bt + bOff[j] + (g + 1) * 32);
      }
      const int kc = c * 4;
      bf16x8 af[4];
#pragma unroll
      for (int i2 = 0; i2 < 4; ++i2)
        af[i2] = *(const bf16x8*)&Ab[(i2 * 16 + lm) * BK + (((quad + kc) ^ l7) * 8)];
#pragma unroll
      for (int i2 = 0; i2 < 4; ++i2)
#pragma unroll
        for (int j = 0; j < 8; ++j)
          acc[i2][j] = MFMA(af[i2], bP[j], acc[i2][j], 0, 0, 0);
      if (g + 1 < NC) {
#pragma unroll
        for (int j = 0; j < 8; ++j) bP[j] = bN[j];
      }
    }
    __syncthreads();
  }

#pragma unroll
  for (int i2 = 0; i2 < 4; ++i2) {
#pragma unroll
    for (int r2 = 0; r2 < 4; ++r2) {
      float s = 0.f, ss = 0.f;
#pragma unroll
      for (int j = 0; j < 8; ++j) {
        float v = fmaxf(acc[i2][j][r2] + prm[wn + j * 16 + lm], 0.f);
        acc[i2][j][r2] = v;
        s += v; ss += v * v;
      }
#pragma unroll
      for (int o = 1; o < 16; o <<= 1) { s += __shfl_xor(s, o, 64); ss += __shfl_xor(ss, o, 64); }
      if (lm == 0) {
        int rowL = i2 * 16 + quad * 4 + r2;
        redS[rowL][wave] = s;
        redSS[rowL][wave] = ss;
      }
    }
  }
  __syncthreads();
#pragma unroll
  for (int i2 = 0; i2 < 4; ++i2) {
#pragma unroll
    for (int r2 = 0; r2 < 4; ++r2) {
      int rowL = i2 * 16 + quad * 4 + r2;
      float ts  = redS[rowL][0] + redS[rowL][1] + redS[rowL][2] + redS[rowL][3];
      float tss = redSS[rowL][0] + redSS[rowL][1] + redSS[rowL][2] + redSS[rowL][3];
      float m = ts * (1.f / 512.f);
      float var = tss * (1.f / 512.f) - m * m;
      float inv = rsqrtf(var + 1e-5f);
      size_t base = (size_t)(rowBase + rowL) * 512;
#pragma unroll
      for (int j = 0; j < 8; ++j) {
        int col = wn + j * 16 + lm;
        float y = (acc[i2][j][r2] - m) * inv * prm[512 + col] + prm[1024 + col];
        C[base + col] = f2b(y);
      }
    }
  }
}

// ---------------------------------------------------------------- route_head: BARRIER-FREE
// 1 wave per block, 16 rows per wave, whole pipeline wave-private.
// Zero __syncthreads: r1/E/h0s/h1s hand-offs are same-wave LDS RAW (compiler
// lgkmcnt-ordered); only manual sync is vmcnt(0)+sched_barrier before the
// first read of the async-staged e-rows (rule: gll16 has no SSA dep).
// LDS 22656 B -> 7 waves/CU, each an independent pipeline.
//   e  [0,8192)      staged e rows (16 x 512, row-swizzled)
//   r1 [8192,10240)  stage0 out (16 x 128); aliased by h1s (f32) in stage3
//   h0s[10240,11328) stage2 out (16 x 68)
__global__ __launch_bounds__(64, 2) void route_head(
    const u16* __restrict__ obs_n, const u16* __restrict__ e,
    const u16* __restrict__ Wr0t, const float* __restrict__ br0,
    const u16* __restrict__ Wr1t, const float* __restrict__ br1,
    const u16* __restrict__ Wh0t, const float* __restrict__ bh0,
    const float* __restrict__ Wh1, const float* __restrict__ bh1,
    const float* __restrict__ Wh2, const float* __restrict__ bh2,
    const float* __restrict__ avail,
    const int* __restrict__ bucket, const int* __restrict__ baseArr,
    const int* __restrict__ cntArr, float* __restrict__ outLogits)
{
  __shared__ __align__(16) u16 sm[11328];   // 22656 B
  const int lane = threadIdx.x;

  int cA0, cA1, cA2, cA3, cA4, cA5, bA0, bA1, bA2, bA3, bA4, bA5;
  {
    int4 ca = *(const int4*)cntArr;  int2 cb = *(const int2*)(cntArr + 4);
    int4 ba = *(const int4*)baseArr; int2 bb = *(const int2*)(baseArr + 4);
    cA0 = ca.x; cA1 = ca.y; cA2 = ca.z; cA3 = ca.w; cA4 = cb.x; cA5 = cb.y;
    bA0 = ba.x; bA1 = ba.y; bA2 = ba.z; bA3 = ba.w; bA4 = bb.x; bA5 = bb.y;
  }
  int role = -1, rem = blockIdx.x, cnt = 0, roleBase = 0;
#define TRY_ROLE(k, ck, bk)                                        \
  if (role < 0) {                                                  \
    int tiles = ((ck) + 15) >> 4;                                  \
    if (rem < tiles) { role = (k); cnt = (ck); roleBase = (bk); }  \
    else rem -= tiles;                                             \
  }
  TRY_ROLE(0, cA0, bA0) TRY_ROLE(1, cA1, bA1) TRY_ROLE(2, cA2, bA2)
  TRY_ROLE(3, cA3, bA3) TRY_ROLE(4, cA4, bA4) TRY_ROLE(5, cA5, bA5)
#undef TRY_ROLE
  if (role < 0) return;
  const int limit = cnt;
  const int rowBase = rem * 16;

  const int quad = lane >> 4, lm = lane & 15;

  // e-staging: 16 rows, one gll16 per row (64 lanes x 16B = 1 row), pre-swizzled src.
#pragma unroll
  for (int lrow = 0; lrow < 16; ++lrow) {
    int i = rowBase + lrow;
    if (i >= limit) i = rowBase;
    int grow = bucket[roleBase + i];
    int sw = (lane & 56) | ((lane ^ lrow) & 7);
    gll16(e + (u32)grow * 512u + (u32)(sw * 8), &sm[lrow * 512]);
  }

  // stage0 A: lane's row = lane&15 of obs_n (direct global)
  int iA = rowBase + lm; if (iA >= limit) iA = rowBase;
  const u16* Ag = obs_n + (size_t)bucket[roleBase + iA] * 256 + quad * 8;

  // ---- stage0: r1 = relu(obs_n[16 rows] @ Wr0k^T + br0)   (16x128, K=256)
  const u16* B0 = Wr0t + (size_t)role * 128 * 256;
  f32x4 acc0[8] = {};
#pragma unroll
  for (int kc = 0; kc < 8; ++kc) {
    bf16x8 a = *(const bf16x8*)(Ag + kc * 32);
#pragma unroll
    for (int j = 0; j < 8; ++j) {
      bf16x8 b = *(const bf16x8*)(B0 + (u32)(j * 16 + lm) * 256u + (u32)(kc * 32 + quad * 8));
      acc0[j] = MFMA(a, b, acc0[j], 0, 0, 0);
    }
  }
  u16* r1 = sm + 8192;
#pragma unroll
  for (int j = 0; j < 8; ++j) {
    float bv = br0[role * 128 + j * 16 + lm];
#pragma unroll
    for (int r2 = 0; r2 < 4; ++r2) {
      int row = quad * 4 + r2;
      int col = j * 16 + lm;
      float v = fmaxf(acc0[j][r2] + bv, 0.f);
      r1[row * 128 + (((col >> 3) ^ (row & 7)) * 8) + (col & 7)] = f2b(v);
    }
  }

  // ---- stage1: E = relu(r1 @ Wr1k^T + br1) + e   (in-place over staged e; 4 col-groups of 128)
  const u16* B1 = Wr1t + (size_t)role * 512 * 128;
#pragma unroll
  for (int g = 0; g < 4; ++g) {
    f32x4 acc1[8] = {};
#pragma unroll
    for (int kc = 0; kc < 4; ++kc) {
      bf16x8 a = *(const bf16x8*)&r1[lm * 128 + (((kc * 4 + quad) ^ (lm & 7)) * 8)];
#pragma unroll
      for (int j = 0; j < 8; ++j) {
        int col = g * 128 + j * 16 + lm;
        bf16x8 b = *(const bf16x8*)(B1 + (u32)col * 128u + (u32)(kc * 32 + quad * 8));
        acc1[j] = MFMA(a, b, acc1[j], 0, 0, 0);
      }
    }
    if (g == 0) {
      // staged e first read below: gll16 has no reg dep -> manual drain + fence
      asm volatile("s_waitcnt vmcnt(0)" ::: "memory");
      __builtin_amdgcn_sched_barrier(0);
    }
#pragma unroll
    for (int j = 0; j < 8; ++j) {
      int col = g * 128 + j * 16 + lm;
      float bv = br1[role * 512 + col];
#pragma unroll
      for (int r2 = 0; r2 < 4; ++r2) {
        int row = quad * 4 + r2;
        int addr = row * 512 + (((col >> 3) ^ (row & 7)) * 8) + (col & 7);
        float v = fmaxf(acc1[j][r2] + bv, 0.f) + b2f(sm[addr]);
        sm[addr] = f2b(v);
      }
    }
  }

  // ---- stage2: h0 = relu(E @ Wh0k^T + bh0)   (16x64, K=512)
  const u16* B2 = Wh0t + (size_t)role * 64 * 512;
  f32x4 acc2[4] = {};
#pragma unroll
  for (int kt = 0; kt < 16; ++kt) {
    bf16x8 a = *(const bf16x8*)&sm[lm * 512 + (((kt * 4 + quad) ^ (lm & 7)) * 8)];
#pragma unroll
    for (int j = 0; j < 4; ++j) {
      bf16x8 b = *(const bf16x8*)(B2 + (u32)(j * 16 + lm) * 512u + (u32)(kt * 32 + quad * 8));
      acc2[j] = MFMA(a, b, acc2[j], 0, 0, 0);
    }
  }
  u16* h0s = sm + 10240;
#pragma unroll
  for (int j = 0; j < 4; ++j) {
    float bv = bh0[role * 64 + j * 16 + lm];
#pragma unroll
    for (int r2 = 0; r2 < 4; ++r2) {
      int row = quad * 4 + r2;
      h0s[row * 68 + j * 16 + lm] = f2b(fmaxf(acc2[j][r2] + bv, 0.f));
    }
  }

  // ---- stage3: per-lane tail (lane covers row lane>>2, cols (lane&3)*8..+8)
  {
    float* h1s = (float*)&sm[8192];   // over r1 (dead after stage1)
    const int r = lane >> 2;
    const int n0 = (lane & 3) * 8;
    const bool valid = (rowBase + r) < limit;
    const float* W1k = Wh1 + (size_t)role * 64 * 32;
    const float* W2k = Wh2 + (size_t)role * 32 * 32;
    float4 a1a = *(const float4*)(bh1 + role * 32 + n0);
    float4 a1b = *(const float4*)(bh1 + role * 32 + n0 + 4);
#pragma unroll 8
    for (int j = 0; j < 64; ++j) {
      float hj = b2f(h0s[r * 68 + j]);
      float4 wa = *(const float4*)(W1k + j * 32 + n0);
      float4 wb = *(const float4*)(W1k + j * 32 + n0 + 4);
      a1a.x += hj * wa.x; a1a.y += hj * wa.y; a1a.z += hj * wa.z; a1a.w += hj * wa.w;
      a1b.x += hj * wb.x; a1b.y += hj * wb.y; a1b.z += hj * wb.z; a1b.w += hj * wb.w;
    }
    a1a.x = fmaxf(a1a.x, 0.f); a1a.y = fmaxf(a1a.y, 0.f);
    a1a.z = fmaxf(a1a.z, 0.f); a1a.w = fmaxf(a1a.w, 0.f);
    a1b.x = fmaxf(a1b.x, 0.f); a1b.y = fmaxf(a1b.y, 0.f);
    a1b.z = fmaxf(a1b.z, 0.f); a1b.w = fmaxf(a1b.w, 0.f);
    *(float4*)(h1s + r * 36 + n0)     = a1a;
    *(float4*)(h1s + r * 36 + n0 + 4) = a1b;
    // same-wave lockstep: all lanes' writes precede reads in program order
    float4 a2a = *(const float4*)(bh2 + role * 32 + n0);
    float4 a2b = *(const float4*)(bh2 + role * 32 + n0 + 4);
#pragma unroll 8
    for (int n = 0; n < 32; ++n) {
      float hn = h1s[r * 36 + n];
      float4 wa = *(const float4*)(W2k + n * 32 + n0);
      float4 wb = *(const float4*)(W2k + n * 32 + n0 + 4);
      a2a.x += hn * wa.x; a2a.y += hn * wa.y; a2a.z += hn * wa.z; a2a.w += hn * wa.w;
      a2b.x += hn * wb.x; a2b.y += hn * wb.y; a2b.z += hn * wb.z; a2b.w += hn * wb.w;
    }
    if (valid) {
      int g = bucket[roleBase + rowBase + r];
      float4 ava = *(const float4*)(avail + (size_t)g * 32 + n0);
      float4 avb = *(const float4*)(avail + (size_t)g * 32 + n0 + 4);
      float4 oa, ob;
      oa.x = (ava.x > 0.5f) ? a2a.x : -1e10f;
      oa.y = (ava.y > 0.5f) ? a2a.y : -1e10f;
      oa.z = (ava.z > 0.5f) ? a2a.z : -1e10f;
      oa.w = (ava.w > 0.5f) ? a2a.w : -1e10f;
      ob.x = (avb.x > 0.5f) ? a2b.x : -1e10f;
      ob.y = (avb.y > 0.5f) ? a2b.y : -1e10f;
      ob.z = (avb.z > 0.5f) ? a2b.z : -1e10f;
      ob.w = (avb.w > 0.5f) ? a2b.w : -1e10f;
      *(float4*)(outLogits + (size_t)g * 32 + n0)     = oa;
      *(float4*)(outLogits + (size_t)g * 32 + n0 + 4) = ob;
    }
  }
}

// ---------------------------------------------------------------- launcher
extern "C" void kernel_launch(void* const* d_in, const int* in_sizes, int n_in,
                              void* d_out, int out_size, void* d_ws, size_t ws_size,
                              hipStream_t stream)
{
  const float* rnn  = (const float*)d_in[0];
  const float* obs  = (const float*)d_in[1];
  const float* avail= (const float*)d_in[3];
  const int*   rid  = (const int*)d_in[4];
  const float* fn_s = (const float*)d_in[5];
  const float* fn_b = (const float*)d_in[6];
  const float* W0   = (const float*)d_in[7];
  const float* b0   = (const float*)d_in[8];
  const float* ln0s = (const float*)d_in[9];
  const float* ln0b = (const float*)d_in[10];
  const float* W1   = (const float*)d_in[11];
  const float* b1   = (const float*)d_in[12];
  const float* ln1s = (const float*)d_in[13];
  const float* ln1b = (const float*)d_in[14];
  const float* Wr0  = (const float*)d_in[15];
  const float* br0  = (const float*)d_in[16];
  const float* Wr1  = (const float*)d_in[17];
  const float* br1  = (const float*)d_in[18];
  const float* Wh0  = (const float*)d_in[19];
  const float* bh0  = (const float*)d_in[20];
  const float* Wh1  = (const float*)d_in[21];
  const float* bh1  = (const float*)d_in[22];
  const float* Wh2  = (const float*)d_in[23];
  const float* bh2  = (const float*)d_in[24];

  const int ROWS = 32768;

  char* w = (char*)d_ws;
  auto carve = [&](size_t bytes) { char* p = w; w += (bytes + 255) & ~(size_t)255; return p; };
  u16* obs_n  = (u16*)carve((size_t)ROWS * 256 * 2);
  u16* bufA   = (u16*)carve((size_t)ROWS * 512 * 2);   // e0
  u16* bufB   = (u16*)carve((size_t)ROWS * 512 * 2);   // e
  u16* W0t    = (u16*)carve((size_t)512 * 256 * 2);
  u16* W1t    = (u16*)carve((size_t)512 * 512 * 2);
  u16* Wr0t   = (u16*)carve((size_t)6 * 128 * 256 * 2);
  u16* Wr1t   = (u16*)carve((size_t)6 * 512 * 128 * 2);
  u16* Wh0t   = (u16*)carve((size_t)6 * 64 * 512 * 2);
  int* bucket = (int*)carve((size_t)ROWS * 4);
  int* blkCnt = (int*)carve((size_t)128 * NROLE * 4);
  int* baseArr= (int*)carve(256);
  int* cntArr = (int*)carve(256);

  float* outLogits = (float*)d_out + (size_t)1024 * 512;

  // mega0: weight transposes + role_count + rnn passthrough
  mega0<<<1408, 256, 0, stream>>>(W0, W1, Wr0, Wr1, Wh0, W0t, W1t, Wr0t, Wr1t, Wh0t,
                                  rid, blkCnt, rnn, (float*)d_out);

  // fused obs-LN + gemm0 + LN0 (blocks 0..511) and fill2 (blocks 512..639)
  g0f<<<640, 256, 0, stream>>>(obs, fn_s, fn_b, W0t, b0, ln0s, ln0b,
                               obs_n, bufA, rid, blkCnt, bucket, baseArr, cntArr);

  // base MLP layer 1 (LN fused, pipelined BK=128)
  gemm_ln<512><<<512, 256, 0, stream>>>(bufA, W1t, b1, ln1s, ln1b, bufB);

  // barrier-free role route + full head (1 wave / 16 rows per block)
  route_head<<<2053, 64, 0, stream>>>(obs_n, bufB, Wr0t, br0, Wr1t, br1, Wh0t, bh0,
                                      Wh1, bh1, Wh2, bh2, avail,
                                      bucket, baseArr, cntArr, outLogits);
}

// Round 6
// 263.935 us; speedup vs baseline: 1.1819x; 1.1819x over previous
//
#include <hip/hip_runtime.h>
#include <stdint.h>

typedef unsigned short u16;
typedef unsigned int u32;

using bf16x8 = __attribute__((ext_vector_type(8))) short;
using f32x4  = __attribute__((ext_vector_type(4))) float;

#define DEVINL __device__ __forceinline__

DEVINL float b2f(u16 u) { return __builtin_bit_cast(float, (u32)u << 16); }
DEVINL u16 f2b(float f) {
  u32 u = __builtin_bit_cast(u32, f);
  u += 0x7FFFu + ((u >> 16) & 1u);   // round-to-nearest-even
  return (u16)(u >> 16);
}

DEVINL void gll16(const u16* src, u16* dst) {
  __builtin_amdgcn_global_load_lds(
      (const __attribute__((address_space(1))) void*)(uintptr_t)src,
      (__attribute__((address_space(3))) void*)(uintptr_t)dst, 16, 0, 0);
}

#define MFMA __builtin_amdgcn_mfma_f32_16x16x32_bf16
#define NROLE 6

// ---------------------------------------------------------------- mega0:
// transposes (blocks 0..1151) | role_count (1152..1279) | rnn copy (1280..1407).
DEVINL void tp_tile(const float* __restrict__ s, u16* __restrict__ d,
                    int R, int C, int bx, int by, int z)
{
  __shared__ u16 tile[32][33];
  const size_t mstride = (size_t)R * C;
  s += (size_t)z * mstride;
  d += (size_t)z * mstride;
  int r0 = bx * 32, c0 = by * 32;
  int tx = threadIdx.x & 31, ty = threadIdx.x >> 5;
#pragma unroll
  for (int i = 0; i < 32; i += 8)
    tile[ty + i][tx] = f2b(s[(size_t)(r0 + ty + i) * C + (c0 + tx)]);
  __syncthreads();
#pragma unroll
  for (int i = 0; i < 32; i += 8)
    d[(size_t)(c0 + ty + i) * R + (r0 + tx)] = tile[tx][ty + i];
}

__global__ __launch_bounds__(256) void mega0(
    const float* W0, const float* W1, const float* Wr0, const float* Wr1, const float* Wh0,
    u16* W0t, u16* W1t, u16* Wr0t, u16* Wr1t, u16* Wh0t,
    const int* __restrict__ rid, int* __restrict__ blkCnt,
    const float* __restrict__ rnn, float* __restrict__ outRnn)
{
  int b = blockIdx.x;
  const int tid = threadIdx.x;
  if (b < 1152) {
    if (b < 128)      {            tp_tile(W0, W0t, 256, 512, b % 8,  b / 8, 0); }
    else if (b < 384) { b -= 128;  tp_tile(W1, W1t, 512, 512, b % 16, b / 16, 0); }
    else if (b < 576) { b -= 384;  int t = b / 8;  tp_tile(Wr0, Wr0t, 256, 128, b % 8,  t % 4,  t / 4); }
    else if (b < 960) { b -= 576;  int t = b / 4;  tp_tile(Wr1, Wr1t, 128, 512, b % 4,  t % 16, t / 16); }
    else              { b -= 960;  int t = b / 16; tp_tile(Wh0, Wh0t, 512, 64,  b % 16, t % 2,  t / 2); }
  } else if (b < 1280) {
    b -= 1152;
    __shared__ int h[NROLE];
    if (tid < NROLE) h[tid] = 0;
    __syncthreads();
    atomicAdd(&h[rid[b * 256 + tid]], 1);
    __syncthreads();
    if (tid < NROLE) blkCnt[b * NROLE + tid] = h[tid];
  } else {
    b -= 1280;
    const float4* src = (const float4*)rnn;
    float4* dst = (float4*)outRnn;
    int base = (b * 256 + tid) * 4;
#pragma unroll
    for (int i = 0; i < 4; ++i) dst[base + i] = src[base + i];
  }
}

// ---------------------------------------------------------------- base2:
// blocks 0..511: fused obs-LN + gemm0 + LN0 + gemm1 + LN1 for 64 rows.
//   e0 (gemm0 output) lives ONLY in LDS -> bufA round-trip (67 MB) eliminated,
//   plus one dispatch + its staging pipeline. Geometry preserved vs the
//   separate kernels: 64 rows/block, full N=512 (B-reuse unchanged).
// blocks 512..639: fill2 (scan + bucket fill), verbatim.
// LDS 67584 B -> 2 blocks/CU:
//   A0  [0,32768)B   64x256 u16 swizzled (g0f layout; dead after gemm0)
//   e0  [0,65536)B   64x512 u16 swizzled (overlays A0; written after B2)
//   red [65536,67584)B  redS 256 f32 | redSS 256 f32
__global__ __launch_bounds__(256, 2) void base2(
    const float* __restrict__ obs, const float* __restrict__ fn_s,
    const float* __restrict__ fn_b, const u16* __restrict__ W0t,
    const float* __restrict__ b0, const float* __restrict__ ln0sc,
    const float* __restrict__ ln0bi, const u16* __restrict__ W1t,
    const float* __restrict__ b1, const float* __restrict__ ln1sc,
    const float* __restrict__ ln1bi, u16* __restrict__ obs_n,
    u16* __restrict__ C,
    const int* __restrict__ rid, const int* __restrict__ blkCnt,
    int* __restrict__ bucket, int* __restrict__ baseArr, int* __restrict__ cntArr)
{
  __shared__ __align__(16) u16 smem[33792];   // 67584 B
  const int tid = threadIdx.x;

  if (blockIdx.x >= 512) {
    // ---- fill2 branch (verbatim)
    const int bx = blockIdx.x - 512;
    int* c = (int*)smem;
    int* preArr = c + 768;
    int* scnt   = c + 776;
    int* sbase  = c + 784;
    int* h      = c + 792;
    for (int i = tid; i < 128 * NROLE; i += 256) c[i] = blkCnt[i];
    if (tid < NROLE) h[tid] = 0;
    __syncthreads();
    if (tid < NROLE) {
      int k = tid, run = 0, pre = 0;
      for (int b = 0; b < 128; ++b) { if (b == bx) pre = run; run += c[b * NROLE + k]; }
      scnt[k] = run; preArr[k] = pre;
    }
    __syncthreads();
    if (tid == 0) {
      int r = 0;
      for (int k = 0; k < NROLE; ++k) { sbase[k] = r; r += scnt[k]; }
    }
    __syncthreads();
    if (bx == 0 && tid < NROLE) { baseArr[tid] = sbase[tid]; cntArr[tid] = scnt[tid]; }
    int i = bx * 256 + tid;
    int k = rid[i];
    int pos = atomicAdd(&h[k], 1);
    bucket[sbase[k] + preArr[k] + pos] = i;
    return;
  }

  float* redS  = (float*)&smem[32768];   // [64][4]
  float* redSS = redS + 256;             // [64][4]
  const int rowBase = blockIdx.x * 64;
  const int lane = tid & 63, wave = tid >> 6;
  const int quad = lane >> 4, lm = lane & 15, l7 = lm & 7;
  const int wn = wave * 128;

  // ---- obs-LN staging (g0f-verbatim): A0 swizzled into smem[0,16384) u16,
  // plus row-major obs_n to global for route stage0.
  {
    const int r = tid >> 2, q = tid & 3;
    const float* xr = obs + (size_t)(rowBase + r) * 256 + q * 64;
    float x[64];
#pragma unroll
    for (int jj = 0; jj < 16; ++jj)
      *(float4*)&x[jj * 4] = *(const float4*)(xr + jj * 4);
    float s = 0.f, s2 = 0.f;
#pragma unroll
    for (int p = 0; p < 64; ++p) { s += x[p]; s2 += x[p] * x[p]; }
    s  += __shfl_xor(s, 1, 64);  s  += __shfl_xor(s, 2, 64);
    s2 += __shfl_xor(s2, 1, 64); s2 += __shfl_xor(s2, 2, 64);
    float m = s * (1.f / 256.f);
    float var = s2 * (1.f / 256.f) - m * m;
    float inv = rsqrtf(var + 1e-5f);
    const float* fs = fn_s + q * 64;
    const float* fb = fn_b + q * 64;
    u16* og = obs_n + (size_t)(rowBase + r) * 256 + q * 64;
#pragma unroll
    for (int j = 0; j < 8; ++j) {
      float4 fs0 = *(const float4*)(fs + j * 8);
      float4 fs1 = *(const float4*)(fs + j * 8 + 4);
      float4 fb0 = *(const float4*)(fb + j * 8);
      float4 fb1 = *(const float4*)(fb + j * 8 + 4);
      u16 yy[8] __attribute__((aligned(16)));
      yy[0] = f2b((x[j*8+0] - m) * inv * fs0.x + fb0.x);
      yy[1] = f2b((x[j*8+1] - m) * inv * fs0.y + fb0.y);
      yy[2] = f2b((x[j*8+2] - m) * inv * fs0.z + fb0.z);
      yy[3] = f2b((x[j*8+3] - m) * inv * fs0.w + fb0.w);
      yy[4] = f2b((x[j*8+4] - m) * inv * fs1.x + fb1.x);
      yy[5] = f2b((x[j*8+5] - m) * inv * fs1.y + fb1.y);
      yy[6] = f2b((x[j*8+6] - m) * inv * fs1.z + fb1.z);
      yy[7] = f2b((x[j*8+7] - m) * inv * fs1.w + fb1.w);
      int cch = q * 8 + j;
      *(uint4*)&smem[r * 256 + ((cch ^ (r & 7)) * 8)] = *(uint4*)yy;
      *(uint4*)(og + j * 8) = *(uint4*)yy;
    }
  }

  // ---- gemm0: acc = A0 @ W0t^T   (K=256, N=512; wave = 128 cols); B ring-2
  u32 bOff0[8];
#pragma unroll
  for (int j = 0; j < 8; ++j)
    bOff0[j] = (u32)(wn + j * 16 + lm) * 256u + (u32)(quad * 8);
  f32x4 acc[4][8] = {};
  bf16x8 bR[2][8];
#pragma unroll
  for (int p = 0; p < 2; ++p)
#pragma unroll
    for (int j = 0; j < 8; ++j)
      bR[p][j] = *(const bf16x8*)(W0t + bOff0[j] + p * 32);
  __syncthreads();   // B1: A0 staged

#pragma unroll
  for (int g = 0; g < 8; ++g) {
    bf16x8 cur[8];
#pragma unroll
    for (int j = 0; j < 8; ++j) cur[j] = bR[g & 1][j];
    if (g + 2 < 8) {
#pragma unroll
      for (int j = 0; j < 8; ++j)
        bR[g & 1][j] = *(const bf16x8*)(W0t + bOff0[j] + (g + 2) * 32);
    }
    const int kc = g * 4;
    bf16x8 af[4];
#pragma unroll
    for (int i2 = 0; i2 < 4; ++i2)
      af[i2] = *(const bf16x8*)&smem[(i2 * 16 + lm) * 256 + (((quad + kc) ^ l7) * 8)];
#pragma unroll
    for (int i2 = 0; i2 < 4; ++i2)
#pragma unroll
      for (int j = 0; j < 8; ++j)
        acc[i2][j] = MFMA(af[i2], cur[j], acc[i2][j], 0, 0, 0);
  }

  // ---- ReLU + LN0 partials (biases in registers)
  {
    float b0v[8];
#pragma unroll
    for (int j = 0; j < 8; ++j) b0v[j] = b0[wn + j * 16 + lm];
#pragma unroll
    for (int i2 = 0; i2 < 4; ++i2) {
#pragma unroll
      for (int r2 = 0; r2 < 4; ++r2) {
        float s = 0.f, ss = 0.f;
#pragma unroll
        for (int j = 0; j < 8; ++j) {
          float v = fmaxf(acc[i2][j][r2] + b0v[j], 0.f);
          acc[i2][j][r2] = v;
          s += v; ss += v * v;
        }
#pragma unroll
        for (int o = 1; o < 16; o <<= 1) { s += __shfl_xor(s, o, 64); ss += __shfl_xor(ss, o, 64); }
        if (lm == 0) {
          int row = i2 * 16 + quad * 4 + r2;
          redS[row * 4 + wave] = s;
          redSS[row * 4 + wave] = ss;
        }
      }
    }
  }
  __syncthreads();   // B2: red0 done AND all A0 reads done (gemm0 complete)

  // ---- LN0 finalize -> e0 bf16 into [0,65536)B (overlays dead A0)
  {
    float s0v[8], s0b[8];
#pragma unroll
    for (int j = 0; j < 8; ++j) {
      s0v[j] = ln0sc[wn + j * 16 + lm];
      s0b[j] = ln0bi[wn + j * 16 + lm];
    }
#pragma unroll
    for (int i2 = 0; i2 < 4; ++i2) {
#pragma unroll
      for (int r2 = 0; r2 < 4; ++r2) {
        int row = i2 * 16 + quad * 4 + r2;
        float ts  = redS[row * 4 + 0] + redS[row * 4 + 1] + redS[row * 4 + 2] + redS[row * 4 + 3];
        float tss = redSS[row * 4 + 0] + redSS[row * 4 + 1] + redSS[row * 4 + 2] + redSS[row * 4 + 3];
        float m = ts * (1.f / 512.f);
        float var = tss * (1.f / 512.f) - m * m;
        float inv = rsqrtf(var + 1e-5f);
#pragma unroll
        for (int j = 0; j < 8; ++j) {
          int col = wn + j * 16 + lm;
          float y = (acc[i2][j][r2] - m) * inv * s0v[j] + s0b[j];
          smem[row * 512 + (((col >> 3) ^ (row & 7)) * 8) + (col & 7)] = f2b(y);
        }
      }
    }
  }
  // gemm1 B preload before the barrier (hide L2 latency under the drain)
  u32 bOff1[8];
#pragma unroll
  for (int j = 0; j < 8; ++j)
    bOff1[j] = (u32)(wn + j * 16 + lm) * 512u + (u32)(quad * 8);
#pragma unroll
  for (int p = 0; p < 2; ++p)
#pragma unroll
    for (int j = 0; j < 8; ++j)
      bR[p][j] = *(const bf16x8*)(W1t + bOff1[j] + p * 32);
  __syncthreads();   // B3: e0 visible; red reusable

  // ---- gemm1: acc = e0 @ W1t^T   (K=512, N=512); B ring-2
#pragma unroll
  for (int i2 = 0; i2 < 4; ++i2)
#pragma unroll
    for (int j = 0; j < 8; ++j)
      acc[i2][j] = (f32x4){0.f, 0.f, 0.f, 0.f};
#pragma unroll
  for (int g = 0; g < 16; ++g) {
    bf16x8 cur[8];
#pragma unroll
    for (int j = 0; j < 8; ++j) cur[j] = bR[g & 1][j];
    if (g + 2 < 16) {
#pragma unroll
      for (int j = 0; j < 8; ++j)
        bR[g & 1][j] = *(const bf16x8*)(W1t + bOff1[j] + (g + 2) * 32);
    }
    const int kc = g * 4;
    bf16x8 af[4];
#pragma unroll
    for (int i2 = 0; i2 < 4; ++i2)
      af[i2] = *(const bf16x8*)&smem[(i2 * 16 + lm) * 512 + (((quad + kc) ^ l7) * 8)];
#pragma unroll
    for (int i2 = 0; i2 < 4; ++i2)
#pragma unroll
      for (int j = 0; j < 8; ++j)
        acc[i2][j] = MFMA(af[i2], cur[j], acc[i2][j], 0, 0, 0);
  }

  // ---- ReLU + LN1 partials
  {
    float b1v[8];
#pragma unroll
    for (int j = 0; j < 8; ++j) b1v[j] = b1[wn + j * 16 + lm];
#pragma unroll
    for (int i2 = 0; i2 < 4; ++i2) {
#pragma unroll
      for (int r2 = 0; r2 < 4; ++r2) {
        float s = 0.f, ss = 0.f;
#pragma unroll
        for (int j = 0; j < 8; ++j) {
          float v = fmaxf(acc[i2][j][r2] + b1v[j], 0.f);
          acc[i2][j][r2] = v;
          s += v; ss += v * v;
        }
#pragma unroll
        for (int o = 1; o < 16; o <<= 1) { s += __shfl_xor(s, o, 64); ss += __shfl_xor(ss, o, 64); }
        if (lm == 0) {
          int row = i2 * 16 + quad * 4 + r2;
          redS[row * 4 + wave] = s;
          redSS[row * 4 + wave] = ss;
        }
      }
    }
  }
  __syncthreads();   // B4: red1 done

  // ---- LN1 finalize -> bufB (global, bf16)
  {
    float s1v[8], s1b[8];
#pragma unroll
    for (int j = 0; j < 8; ++j) {
      s1v[j] = ln1sc[wn + j * 16 + lm];
      s1b[j] = ln1bi[wn + j * 16 + lm];
    }
#pragma unroll
    for (int i2 = 0; i2 < 4; ++i2) {
#pragma unroll
      for (int r2 = 0; r2 < 4; ++r2) {
        int row = i2 * 16 + quad * 4 + r2;
        float ts  = redS[row * 4 + 0] + redS[row * 4 + 1] + redS[row * 4 + 2] + redS[row * 4 + 3];
        float tss = redSS[row * 4 + 0] + redSS[row * 4 + 1] + redSS[row * 4 + 2] + redSS[row * 4 + 3];
        float m = ts * (1.f / 512.f);
        float var = tss * (1.f / 512.f) - m * m;
        float inv = rsqrtf(var + 1e-5f);
        size_t base = (size_t)(rowBase + row) * 512;
#pragma unroll
        for (int j = 0; j < 8; ++j) {
          int col = wn + j * 16 + lm;
          float y = (acc[i2][j][r2] - m) * inv * s1v[j] + s1b[j];
          C[base + col] = f2b(y);
        }
      }
    }
  }
}

// ---------------------------------------------------------------- route_head (round-2 verified, 67-68 us)
// LDS = 40960 B -> 4 blocks/CU. Stage1 split into two 64-col halves to keep
// live regs < 128.
//   ea [0,16384) u16  |  scratch [16384,20480) u16:
//     r1 (stage0->1) then h0s (stage2->3) then h1s f32 (aliased)
__global__ __launch_bounds__(256, 4) void route_head(
    const u16* __restrict__ obs_n, const u16* __restrict__ e,
    const u16* __restrict__ Wr0t, const float* __restrict__ br0,
    const u16* __restrict__ Wr1t, const float* __restrict__ br1,
    const u16* __restrict__ Wh0t, const float* __restrict__ bh0,
    const float* __restrict__ Wh1, const float* __restrict__ bh1,
    const float* __restrict__ Wh2, const float* __restrict__ bh2,
    const float* __restrict__ avail,
    const int* __restrict__ bucket, const int* __restrict__ baseArr,
    const int* __restrict__ cntArr, float* __restrict__ outLogits)
{
  __shared__ __align__(16) u16 sm[20480];   // 40960 B
  const int tid = threadIdx.x;

  int cA0, cA1, cA2, cA3, cA4, cA5, bA0, bA1, bA2, bA3, bA4, bA5;
  {
    int4 ca = *(const int4*)cntArr;  int2 cb = *(const int2*)(cntArr + 4);
    int4 ba = *(const int4*)baseArr; int2 bb = *(const int2*)(baseArr + 4);
    cA0 = ca.x; cA1 = ca.y; cA2 = ca.z; cA3 = ca.w; cA4 = cb.x; cA5 = cb.y;
    bA0 = ba.x; bA1 = ba.y; bA2 = ba.z; bA3 = ba.w; bA4 = bb.x; bA5 = bb.y;
  }
  int role = -1, rem = blockIdx.x, cnt = 0, roleBase = 0;
#define TRY_ROLE(k, ck, bk)                                        \
  if (role < 0) {                                                  \
    int tiles = ((ck) + 31) >> 5;                                  \
    if (rem < tiles) { role = (k); cnt = (ck); roleBase = (bk); }  \
    else rem -= tiles;                                             \
  }
  TRY_ROLE(0, cA0, bA0) TRY_ROLE(1, cA1, bA1) TRY_ROLE(2, cA2, bA2)
  TRY_ROLE(3, cA3, bA3) TRY_ROLE(4, cA4, bA4) TRY_ROLE(5, cA5, bA5)
#undef TRY_ROLE
  if (role < 0) return;
  const int limit = cnt;
  const int rowBase = rem * 32;

  const int lane = tid & 63, wave = tid >> 6;
  const int quad = lane >> 4, lm = lane & 15, l7 = lm & 7;

#pragma unroll
  for (int r = 0; r < 8; ++r) {
    int lrow = r * 4 + wave;
    int i = rowBase + lrow;
    if (i >= limit) i = rowBase;
    int grow = bucket[roleBase + i];
    int chunk = tid & 63;
    int sw = (chunk & 56) | ((chunk ^ lrow) & 7);
    gll16(e + (u32)grow * 512u + (u32)(sw * 8), &sm[r * 2048 + wave * 512]);
  }

  int growA0, growA1;
  {
    int i0 = rowBase + lm;        if (i0 >= limit) i0 = rowBase;
    int i1 = rowBase + 16 + lm;   if (i1 >= limit) i1 = rowBase;
    growA0 = bucket[roleBase + i0];
    growA1 = bucket[roleBase + i1];
  }
  const u16* Ag0 = obs_n + (size_t)growA0 * 256;
  const u16* Ag1 = obs_n + (size_t)growA1 * 256;

  // ---- stage0
  const int wn0 = wave * 32;
  const u16* B0 = Wr0t + (size_t)role * 128 * 256;
  f32x4 acc0[2][2] = {};
  bf16x8 b0R[2][2];
#pragma unroll
  for (int p = 0; p < 2; ++p)
#pragma unroll
    for (int j = 0; j < 2; ++j)
      b0R[p][j] = *(const bf16x8*)(B0 + (u32)(wn0 + j * 16 + lm) * 256u + (u32)(quad * 8 + p * 32));
  bf16x8 aR[4][2];
#pragma unroll
  for (int p = 0; p < 4; ++p) {
    aR[p][0] = *(const bf16x8*)(Ag0 + (u32)(quad * 8 + p * 32));
    aR[p][1] = *(const bf16x8*)(Ag1 + (u32)(quad * 8 + p * 32));
  }
  float bias0[2] = { br0[role * 128 + wn0 + lm], br0[role * 128 + wn0 + 16 + lm] };
#pragma unroll
  for (int it = 0; it < 8; ++it) {
    bf16x8 a0 = aR[it & 3][0], a1 = aR[it & 3][1];
    bf16x8 cur0 = b0R[it & 1][0], cur1 = b0R[it & 1][1];
    if (it + 2 < 8) {
#pragma unroll
      for (int j = 0; j < 2; ++j)
        b0R[it & 1][j] = *(const bf16x8*)(B0 + (u32)(wn0 + j * 16 + lm) * 256u + (u32)(quad * 8 + (it + 2) * 32));
    }
    if (it + 4 < 8) {
      aR[it & 3][0] = *(const bf16x8*)(Ag0 + (u32)(quad * 8 + (it + 4) * 32));
      aR[it & 3][1] = *(const bf16x8*)(Ag1 + (u32)(quad * 8 + (it + 4) * 32));
    }
    acc0[0][0] = MFMA(a0, cur0, acc0[0][0], 0, 0, 0);
    acc0[0][1] = MFMA(a0, cur1, acc0[0][1], 0, 0, 0);
    acc0[1][0] = MFMA(a1, cur0, acc0[1][0], 0, 0, 0);
    acc0[1][1] = MFMA(a1, cur1, acc0[1][1], 0, 0, 0);
  }
  u16* r1 = sm + 16384;
#pragma unroll
  for (int i2 = 0; i2 < 2; ++i2) {
#pragma unroll
    for (int r2 = 0; r2 < 4; ++r2) {
      int row = i2 * 16 + quad * 4 + r2;
#pragma unroll
      for (int j = 0; j < 2; ++j) {
        int col = wn0 + j * 16 + lm;
        float v = fmaxf(acc0[i2][j][r2] + bias0[j], 0.f);
        r1[row * 128 + (((col >> 3) ^ (row & 7)) * 8) + (col & 7)] = f2b(v);
      }
    }
  }
  __syncthreads();   // B1: r1 ready; drains e-staging vmcnt

  // ---- stage1: two 64-col halves
  const int wn1 = wave * 128;
  const u16* B1 = Wr1t + (size_t)role * 512 * 128;
#pragma unroll
  for (int h = 0; h < 2; ++h) {
    const int wnh = wn1 + h * 64;
    float b1v[4];
#pragma unroll
    for (int j = 0; j < 4; ++j) b1v[j] = br1[role * 512 + wnh + j * 16 + lm];
    f32x4 acc1[2][4] = {};
    bf16x8 b1P[4];
#pragma unroll
    for (int j = 0; j < 4; ++j)
      b1P[j] = *(const bf16x8*)(B1 + (u32)(wnh + j * 16 + lm) * 128u + (u32)(quad * 8));
#pragma unroll
    for (int kk = 0; kk < 128; kk += 32) {
      bf16x8 b1N[4];
      if (kk + 32 < 128) {
#pragma unroll
        for (int j = 0; j < 4; ++j)
          b1N[j] = *(const bf16x8*)(B1 + (u32)(wnh + j * 16 + lm) * 128u + (u32)(quad * 8 + kk + 32));
      }
      const int kc = kk >> 3;
      bf16x8 af[2];
#pragma unroll
      for (int i2 = 0; i2 < 2; ++i2)
        af[i2] = *(const bf16x8*)&r1[(i2 * 16 + lm) * 128 + (((quad + kc) ^ l7) * 8)];
#pragma unroll
      for (int i2 = 0; i2 < 2; ++i2)
#pragma unroll
        for (int j = 0; j < 4; ++j)
          acc1[i2][j] = MFMA(af[i2], b1P[j], acc1[i2][j], 0, 0, 0);
      if (kk + 32 < 128) {
#pragma unroll
        for (int j = 0; j < 4; ++j) b1P[j] = b1N[j];
      }
    }
#pragma unroll
    for (int i2 = 0; i2 < 2; ++i2) {
#pragma unroll
      for (int r2 = 0; r2 < 4; ++r2) {
        int row = i2 * 16 + quad * 4 + r2;
#pragma unroll
        for (int j = 0; j < 4; ++j) {
          int col = wnh + j * 16 + lm;
          int addr = row * 512 + (((col >> 3) ^ (row & 7)) * 8) + (col & 7);
          float v = fmaxf(acc1[i2][j][r2] + b1v[j], 0.f) + b2f(sm[addr]);
          sm[addr] = f2b(v);
        }
      }
    }
  }
  __syncthreads();

  // ---- stage2
  const int wn2 = wave * 16;
  const u16* B2 = Wh0t + (size_t)role * 64 * 512;
  float b2v = bh0[role * 64 + wn2 + lm];
  f32x4 acc2[2] = {};
  bf16x8 b2R[4];
#pragma unroll
  for (int p = 0; p < 4; ++p)
    b2R[p] = *(const bf16x8*)(B2 + (u32)(wn2 + lm) * 512u + (u32)(quad * 8 + p * 32));
#pragma unroll
  for (int it = 0; it < 16; ++it) {
    bf16x8 cur = b2R[it & 3];
    if (it + 4 < 16)
      b2R[it & 3] = *(const bf16x8*)(B2 + (u32)(wn2 + lm) * 512u + (u32)(quad * 8 + (it + 4) * 32));
    const int kc = it * 4;
    bf16x8 af[2];
#pragma unroll
    for (int i2 = 0; i2 < 2; ++i2)
      af[i2] = *(const bf16x8*)&sm[(i2 * 16 + lm) * 512 + (((quad + kc) ^ l7) * 8)];
#pragma unroll
    for (int i2 = 0; i2 < 2; ++i2)
      acc2[i2] = MFMA(af[i2], cur, acc2[i2], 0, 0, 0);
  }
  u16* h0s = sm + 16384;
#pragma unroll
  for (int i2 = 0; i2 < 2; ++i2) {
#pragma unroll
    for (int r2 = 0; r2 < 4; ++r2) {
      int row = i2 * 16 + quad * 4 + r2;
      int col = wn2 + lm;
      h0s[row * 68 + col] = f2b(fmaxf(acc2[i2][r2] + b2v, 0.f));
    }
  }
  __syncthreads();

  // ---- stage3
  {
    float* h1s = (float*)&sm[16384];
    const int r = tid >> 3;
    const int n0 = (tid & 7) * 4;
    const bool valid = (rowBase + r) < limit;
    const float* W1k = Wh1 + (size_t)role * 64 * 32;
    const float* W2k = Wh2 + (size_t)role * 32 * 32;
    float4 a1 = *(const float4*)(bh1 + role * 32 + n0);
#pragma unroll 8
    for (int j = 0; j < 64; ++j) {
      float hj = b2f(h0s[r * 68 + j]);
      float4 wv = *(const float4*)(W1k + j * 32 + n0);
      a1.x += hj * wv.x; a1.y += hj * wv.y; a1.z += hj * wv.z; a1.w += hj * wv.w;
    }
    a1.x = fmaxf(a1.x, 0.f); a1.y = fmaxf(a1.y, 0.f);
    a1.z = fmaxf(a1.z, 0.f); a1.w = fmaxf(a1.w, 0.f);
    __syncthreads();
    h1s[r * 36 + n0 + 0] = a1.x;
    h1s[r * 36 + n0 + 1] = a1.y;
    h1s[r * 36 + n0 + 2] = a1.z;
    h1s[r * 36 + n0 + 3] = a1.w;
    __syncthreads();
    float4 a2 = *(const float4*)(bh2 + role * 32 + n0);
#pragma unroll 8
    for (int n = 0; n < 32; ++n) {
      float hn = h1s[r * 36 + n];
      float4 wv = *(const float4*)(W2k + n * 32 + n0);
      a2.x += hn * wv.x; a2.y += hn * wv.y; a2.z += hn * wv.z; a2.w += hn * wv.w;
    }
    if (valid) {
      int g = bucket[roleBase + rowBase + r];
      float4 av = *(const float4*)(avail + (size_t)g * 32 + n0);
      float4 o;
      o.x = (av.x > 0.5f) ? a2.x : -1e10f;
      o.y = (av.y > 0.5f) ? a2.y : -1e10f;
      o.z = (av.z > 0.5f) ? a2.z : -1e10f;
      o.w = (av.w > 0.5f) ? a2.w : -1e10f;
      *(float4*)(outLogits + (size_t)g * 32 + n0) = o;
    }
  }
}

// ---------------------------------------------------------------- launcher
extern "C" void kernel_launch(void* const* d_in, const int* in_sizes, int n_in,
                              void* d_out, int out_size, void* d_ws, size_t ws_size,
                              hipStream_t stream)
{
  const float* rnn  = (const float*)d_in[0];
  const float* obs  = (const float*)d_in[1];
  const float* avail= (const float*)d_in[3];
  const int*   rid  = (const int*)d_in[4];
  const float* fn_s = (const float*)d_in[5];
  const float* fn_b = (const float*)d_in[6];
  const float* W0   = (const float*)d_in[7];
  const float* b0   = (const float*)d_in[8];
  const float* ln0s = (const float*)d_in[9];
  const float* ln0b = (const float*)d_in[10];
  const float* W1   = (const float*)d_in[11];
  const float* b1   = (const float*)d_in[12];
  const float* ln1s = (const float*)d_in[13];
  const float* ln1b = (const float*)d_in[14];
  const float* Wr0  = (const float*)d_in[15];
  const float* br0  = (const float*)d_in[16];
  const float* Wr1  = (const float*)d_in[17];
  const float* br1  = (const float*)d_in[18];
  const float* Wh0  = (const float*)d_in[19];
  const float* bh0  = (const float*)d_in[20];
  const float* Wh1  = (const float*)d_in[21];
  const float* bh1  = (const float*)d_in[22];
  const float* Wh2  = (const float*)d_in[23];
  const float* bh2  = (const float*)d_in[24];

  const int ROWS = 32768;

  char* w = (char*)d_ws;
  auto carve = [&](size_t bytes) { char* p = w; w += (bytes + 255) & ~(size_t)255; return p; };
  u16* obs_n  = (u16*)carve((size_t)ROWS * 256 * 2);
  u16* bufB   = (u16*)carve((size_t)ROWS * 512 * 2);   // e
  u16* W0t    = (u16*)carve((size_t)512 * 256 * 2);
  u16* W1t    = (u16*)carve((size_t)512 * 512 * 2);
  u16* Wr0t   = (u16*)carve((size_t)6 * 128 * 256 * 2);
  u16* Wr1t   = (u16*)carve((size_t)6 * 512 * 128 * 2);
  u16* Wh0t   = (u16*)carve((size_t)6 * 64 * 512 * 2);
  int* bucket = (int*)carve((size_t)ROWS * 4);
  int* blkCnt = (int*)carve((size_t)128 * NROLE * 4);
  int* baseArr= (int*)carve(256);
  int* cntArr = (int*)carve(256);

  float* outLogits = (float*)d_out + (size_t)1024 * 512;

  // mega0: weight transposes + role_count + rnn passthrough
  mega0<<<1408, 256, 0, stream>>>(W0, W1, Wr0, Wr1, Wh0, W0t, W1t, Wr0t, Wr1t, Wh0t,
                                  rid, blkCnt, rnn, (float*)d_out);

  // fused obs-LN + gemm0 + LN0 + gemm1 + LN1 (blocks 0..511) and fill2 (512..639)
  base2<<<640, 256, 0, stream>>>(obs, fn_s, fn_b, W0t, b0, ln0s, ln0b,
                                 W1t, b1, ln1s, ln1b, obs_n, bufB,
                                 rid, blkCnt, bucket, baseArr, cntArr);

  // fused role route + full head (round-2 verified)
  route_head<<<1029, 256, 0, stream>>>(obs_n, bufB, Wr0t, br0, Wr1t, br1, Wh0t, bh0,
                                       Wh1, bh1, Wh2, bh2, avail,
                                       bucket, baseArr, cntArr, outLogits);
}